// Round 4
// baseline (398.340 us; speedup 1.0000x reference)
//
#include <hip/hip_runtime.h>
#include <hip/hip_bf16.h>

// LSTM B=8192,T=512,I=3,H=25 + linear[H->1], bf16 MFMA 16x16x32.
// R16: REGISTER-CLOSED RECURRENCE - zero LDS, zero barriers, zero shuffles.
// R15 post-mortem: barrier-free was right, but the step kept an LDS round
// trip (ds_read 120 + in-order ds_writes 120) on the critical path and with
// 1 wave/SIMD every cycle of it was exposed (1392 cy/step measured).
// Fix: choose BOTH free permutations (unit -> C-row, k-slot -> unit) so each
// lane PRODUCES exactly the h values its own next-step B-frag consumes:
//   lane (q,n): C rows 4q..4q+3 of MFMA m = unit U(q,m), gates 0..3
//   lane (q,n): B-frag k-slots q*8..q*8+7 of column n
//   U(0,m)=m (m<4; m=4..6 dummy zero rows), U(1,m)=4+m, U(2,m)=11+m,
//   U(3,m)=18+m;  k-slot map V: k4..7->u0..3, k8..14->u4..10 (k15 pad),
//   k16..22->u11..17 (k23 pad), k24..30->u18..24 (k31 pad)
// h(t) -> frag(t+1) is then 4 bf16 packs + 4 selects (q0 x/bias slots) -
// pure VALU. Critical path ~200cy < trans issue ~500cy -> issue-bound.
// Kept: reg ping-pong x prefetch, -K1/-K2 prescale folded into A, identical
// activation math/clamps as the passing R12/R15 kernels.
// 512 single-wave blocks -> 2 waves/CU on separate SIMDs (own trans pipes).

#define TSTEPS 512
#define ISZ 3
#define HSZ 25
#define NF 7            // MFMA fragments (112 rows = 25 units*4 gates + 12 pad)

typedef __attribute__((ext_vector_type(8))) short bf16x8;
typedef __attribute__((ext_vector_type(4))) float f32x4;
typedef __attribute__((ext_vector_type(4))) int i32x4;

__device__ __forceinline__ unsigned short bf16_bits(float v) {
    return __builtin_bit_cast(unsigned short, __float2bfloat16(v));
}
__device__ __forceinline__ unsigned int pack_bf16(float lo, float hi) {
    return ((unsigned int)bf16_bits(hi) << 16) | (unsigned int)bf16_bits(lo);
}

__global__ __launch_bounds__(64) void lstm_wave(
    const float* __restrict__ x,      // [B, T, I]
    const float* __restrict__ w_ih,   // [4H, I]
    const float* __restrict__ w_hh,   // [4H, H]
    const float* __restrict__ b_ih,   // [4H]
    const float* __restrict__ b_hh,   // [4H]
    const float* __restrict__ w_lin,  // [1, H]
    const float* __restrict__ b_lin,  // [1]
    float* __restrict__ out)          // [B, 1]
{
    const int lane = threadIdx.x;     // single wave
    const int n = lane & 15;          // batch col
    const int q = lane >> 4;          // quad
    const int b0 = blockIdx.x * 16;

    const float K1 = 1.442695040888963f;   // log2 e
    const float K2 = 2.885390081777927f;   // 2 log2 e

    // ---- register A fragments; prescale -K1 (i,f,o) / -K2 (g) folded in ----
    // A_m[row rr=n][k=q*8+j]; row rr -> unit U(rr>>2, m), gate rr&3.
    // k: 0..2 w_ih, 3 bias, >=4 w_hh column of unit V(k) (pads zero).
    bf16x8 afrag[NF];
    #pragma unroll
    for (int m = 0; m < NF; ++m) {
        const int uq = n >> 2, g = n & 3;
        const int uu = (uq == 0) ? (m < 4 ? m : -1)
                     : (uq == 1) ? 4 + m
                     : (uq == 2) ? 11 + m
                                 : 18 + m;
        #pragma unroll
        for (int j = 0; j < 8; ++j) {
            const int k = q * 8 + j;
            float v = 0.0f;
            if (uu >= 0) {
                const int orow = g * HSZ + uu;         // original i,f,g,o order
                if (k < ISZ)            v = w_ih[orow * ISZ + k];
                else if (k == ISZ)      v = b_ih[orow] + b_hh[orow];
                else {
                    const int vk = (k < 15) ? k - 4
                                 : (k == 15) ? -1
                                 : (k < 23) ? k - 5
                                 : (k == 23) ? -1
                                 : (k < 31) ? k - 6 : -1;
                    if (vk >= 0) v = w_hh[orow * HSZ + vk];
                }
                v *= (g == 2) ? -K2 : -K1;
            }
            afrag[m][j] = (short)bf16_bits(v);
        }
    }

    float cst[NF], hst[NF];
    #pragma unroll
    for (int m = 0; m < NF; ++m) { cst[m] = 0.f; hst[m] = 0.f; }

    // ---- x prefetch: 3 x float4 per 4-step group, reg ping-pong ----
    const float* __restrict__ xg = x + (size_t)(b0 + n) * (TSTEPS * ISZ);
    float4 a0 = ((const float4*)xg)[0];
    float4 a1 = ((const float4*)xg)[1];
    float4 a2 = ((const float4*)xg)[2];

    const f32x4 zacc = {0.f, 0.f, 0.f, 0.f};

    auto step = [&](float x0, float x1, float x2) {
        // build next B-frag from own registers (h(t-1), x(t)); pads = 0
        const unsigned p0 = pack_bf16(hst[0], hst[1]);
        const unsigned p1 = pack_bf16(hst[2], hst[3]);
        const unsigned p2 = pack_bf16(hst[4], hst[5]);
        const unsigned p3 = pack_bf16(hst[6], 0.0f);
        const unsigned f0 = pack_bf16(x0, x1);
        const unsigned f1 = pack_bf16(x2, 1.0f);
        i32x4 fi;
        fi[0] = (q == 0) ? (int)f0 : (int)p0;
        fi[1] = (q == 0) ? (int)f1 : (int)p1;
        fi[2] = (q == 0) ? (int)p0 : (int)p2;
        fi[3] = (q == 0) ? (int)p1 : (int)p3;
        const bf16x8 frag = __builtin_bit_cast(bf16x8, fi);

        #pragma unroll
        for (int m = 0; m < NF; ++m) {
            const f32x4 acc = __builtin_amdgcn_mfma_f32_16x16x32_bf16(
                afrag[m], frag, zacc, 0, 0, 0);
            // acts: acc already -K1/-K2 prescaled; same math/clamps as R12
            const float e0 = __builtin_amdgcn_exp2f(acc[0]);
            const float e1 = __builtin_amdgcn_exp2f(acc[1]);
            const float e2 = __builtin_amdgcn_exp2f(fminf(acc[2], 126.0f));
            const float e3 = __builtin_amdgcn_exp2f(acc[3]);
            const float f  = __builtin_amdgcn_rcpf(1.0f + e1);
            const float ig = (1.0f - e2) *
                __builtin_amdgcn_rcpf((1.0f + e0) * (1.0f + e2));
            cst[m] = fmaf(f, cst[m], ig);
            const float ec = __builtin_amdgcn_exp2f(fminf(-K2 * cst[m], 126.0f));
            hst[m] = (1.0f - ec) *
                __builtin_amdgcn_rcpf((1.0f + e3) * (1.0f + ec));
        }
    };

    #pragma unroll 1
    for (int g = 0; g < TSTEPS / 4; ++g) {
        // prefetch next 4-step group while computing this one
        const float4* __restrict__ pn =
            (const float4*)(xg + (size_t)((g < 127 ? g + 1 : 127) * 12));
        const float4 n0 = pn[0], n1 = pn[1], n2 = pn[2];
        step(a0.x, a0.y, a0.z);
        step(a0.w, a1.x, a1.y);
        step(a1.z, a1.w, a2.x);
        step(a2.y, a2.z, a2.w);
        a0 = n0; a1 = n1; a2 = n2;
    }

    // ---- final linear: out[b] = sum_u w_lin[u]*h[u] + b_lin ----
    const int ubase = (q == 0) ? 0 : (q == 1) ? 4 : (q == 2) ? 11 : 18;
    float v = 0.f;
    #pragma unroll
    for (int m = 0; m < NF; ++m) {
        if ((q != 0) || (m < 4)) v = fmaf(w_lin[ubase + m], hst[m], v);
    }
    v += __shfl_xor(v, 16);
    v += __shfl_xor(v, 32);
    if (lane < 16) out[b0 + n] = v + b_lin[0];
}

extern "C" void kernel_launch(void* const* d_in, const int* in_sizes, int n_in,
                              void* d_out, int out_size, void* d_ws, size_t ws_size,
                              hipStream_t stream) {
    const float* x     = (const float*)d_in[0];
    const float* w_ih  = (const float*)d_in[1];
    const float* w_hh  = (const float*)d_in[2];
    const float* b_ih  = (const float*)d_in[3];
    const float* b_hh  = (const float*)d_in[4];
    const float* w_lin = (const float*)d_in[5];
    const float* b_lin = (const float*)d_in[6];
    float* out = (float*)d_out;

    lstm_wave<<<8192 / 16, 64, 0, stream>>>(x, w_ih, w_hh, b_ih, b_hh,
                                            w_lin, b_lin, out);
}

// Round 5
// 367.553 us; speedup vs baseline: 1.0838x; 1.0838x over previous
//
#include <hip/hip_runtime.h>
#include <hip/hip_bf16.h>

// LSTM B=8192,T=512,I=3,H=25 + linear[H->1], bf16 MFMA 16x16x32.
// R17: R16 + REGISTER BUDGET + STAGE-PARALLEL ACTS.
// R16 post-mortem: register-closed recurrence worked (0 LDS, 0 conflicts)
// but compiler capped at 48 VGPRs (< the ~54 live minimum) and SERIALIZED
// the 7 per-unit activation chains -> 1594cy/step, 1060 of them stalls.
// Fixes:
//  - __launch_bounds__(64, 1): 1 wave/EU target -> ~512 VGPR budget.
//    (512 blocks / 256 CU = 2 waves/CU on 2 SIMDs; low occupancy is the
//    design, not an accident.)
//  - stage-parallel acts: all 28 gate-exps, then all rcp/c-updates, then
//    all 7 ec-exps, then all 7 h's. Each stage = 7-28 INDEPENDENT ops so
//    trans latency (~10cy) hides under sibling issue. Same math/clamps.
// Kept from R16: dual free permutations making h(t)->B-frag(t+1) pure
// per-lane register packing (4 packs + 4 selects), reg ping-pong x
// prefetch, -K1/-K2 prescale folded into A rows.
// Issue floor ~500cy/step (56 trans x 4cy dominates) -> ~107us predicted.

#define TSTEPS 512
#define ISZ 3
#define HSZ 25
#define NF 7            // MFMA fragments (112 rows = 25 units*4 gates + 12 pad)

typedef __attribute__((ext_vector_type(8))) short bf16x8;
typedef __attribute__((ext_vector_type(4))) float f32x4;
typedef __attribute__((ext_vector_type(4))) int i32x4;

__device__ __forceinline__ unsigned short bf16_bits(float v) {
    return __builtin_bit_cast(unsigned short, __float2bfloat16(v));
}
__device__ __forceinline__ unsigned int pack_bf16(float lo, float hi) {
    return ((unsigned int)bf16_bits(hi) << 16) | (unsigned int)bf16_bits(lo);
}

__global__ __launch_bounds__(64, 1) void lstm_wave(
    const float* __restrict__ x,      // [B, T, I]
    const float* __restrict__ w_ih,   // [4H, I]
    const float* __restrict__ w_hh,   // [4H, H]
    const float* __restrict__ b_ih,   // [4H]
    const float* __restrict__ b_hh,   // [4H]
    const float* __restrict__ w_lin,  // [1, H]
    const float* __restrict__ b_lin,  // [1]
    float* __restrict__ out)          // [B, 1]
{
    const int lane = threadIdx.x;     // single wave
    const int n = lane & 15;          // batch col
    const int q = lane >> 4;          // quad
    const int b0 = blockIdx.x * 16;

    const float K1 = 1.442695040888963f;   // log2 e
    const float K2 = 2.885390081777927f;   // 2 log2 e

    // ---- register A fragments; prescale -K1 (i,f,o) / -K2 (g) folded in ----
    // A_m[row rr=n][k=q*8+j]; row rr -> unit U(rr>>2, m), gate rr&3.
    // k: 0..2 w_ih, 3 bias, >=4 w_hh column of unit V(k) (pads zero).
    bf16x8 afrag[NF];
    #pragma unroll
    for (int m = 0; m < NF; ++m) {
        const int uq = n >> 2, g = n & 3;
        const int uu = (uq == 0) ? (m < 4 ? m : -1)
                     : (uq == 1) ? 4 + m
                     : (uq == 2) ? 11 + m
                                 : 18 + m;
        #pragma unroll
        for (int j = 0; j < 8; ++j) {
            const int k = q * 8 + j;
            float v = 0.0f;
            if (uu >= 0) {
                const int orow = g * HSZ + uu;         // original i,f,g,o order
                if (k < ISZ)            v = w_ih[orow * ISZ + k];
                else if (k == ISZ)      v = b_ih[orow] + b_hh[orow];
                else {
                    const int vk = (k < 15) ? k - 4
                                 : (k == 15) ? -1
                                 : (k < 23) ? k - 5
                                 : (k == 23) ? -1
                                 : (k < 31) ? k - 6 : -1;
                    if (vk >= 0) v = w_hh[orow * HSZ + vk];
                }
                v *= (g == 2) ? -K2 : -K1;
            }
            afrag[m][j] = (short)bf16_bits(v);
        }
    }

    float cst[NF], hst[NF];
    #pragma unroll
    for (int m = 0; m < NF; ++m) { cst[m] = 0.f; hst[m] = 0.f; }

    // ---- x prefetch: 3 x float4 per 4-step group, reg ping-pong ----
    const float* __restrict__ xg = x + (size_t)(b0 + n) * (TSTEPS * ISZ);
    float4 a0 = ((const float4*)xg)[0];
    float4 a1 = ((const float4*)xg)[1];
    float4 a2 = ((const float4*)xg)[2];

    const f32x4 zacc = {0.f, 0.f, 0.f, 0.f};

    auto step = [&](float x0, float x1, float x2) {
        // build next B-frag from own registers (h(t-1), x(t)); pads = 0
        const unsigned p0 = pack_bf16(hst[0], hst[1]);
        const unsigned p1 = pack_bf16(hst[2], hst[3]);
        const unsigned p2 = pack_bf16(hst[4], hst[5]);
        const unsigned p3 = pack_bf16(hst[6], 0.0f);
        const unsigned f0 = pack_bf16(x0, x1);
        const unsigned f1 = pack_bf16(x2, 1.0f);
        i32x4 fi;
        fi[0] = (q == 0) ? (int)f0 : (int)p0;
        fi[1] = (q == 0) ? (int)f1 : (int)p1;
        fi[2] = (q == 0) ? (int)p0 : (int)p2;
        fi[3] = (q == 0) ? (int)p1 : (int)p3;
        const bf16x8 frag = __builtin_bit_cast(bf16x8, fi);

        // ---- all MFMAs (independent, share frag) ----
        f32x4 acc[NF];
        #pragma unroll
        for (int m = 0; m < NF; ++m)
            acc[m] = __builtin_amdgcn_mfma_f32_16x16x32_bf16(
                afrag[m], frag, zacc, 0, 0, 0);

        // ---- stage 1: all gate exps (28 independent trans) ----
        float e0[NF], e1[NF], e2[NF], e3[NF];
        #pragma unroll
        for (int m = 0; m < NF; ++m) {
            e0[m] = __builtin_amdgcn_exp2f(acc[m][0]);
            e1[m] = __builtin_amdgcn_exp2f(acc[m][1]);
            e2[m] = __builtin_amdgcn_exp2f(fminf(acc[m][2], 126.0f));
            e3[m] = __builtin_amdgcn_exp2f(acc[m][3]);
        }
        // ---- stage 2: f/ig rcps + c update (7 independent chains) ----
        #pragma unroll
        for (int m = 0; m < NF; ++m) {
            const float f  = __builtin_amdgcn_rcpf(1.0f + e1[m]);
            const float ig = (1.0f - e2[m]) *
                __builtin_amdgcn_rcpf((1.0f + e0[m]) * (1.0f + e2[m]));
            cst[m] = fmaf(f, cst[m], ig);
        }
        // ---- stage 3: all ec exps (7 independent trans) ----
        float ec[NF];
        #pragma unroll
        for (int m = 0; m < NF; ++m)
            ec[m] = __builtin_amdgcn_exp2f(fminf(-K2 * cst[m], 126.0f));
        // ---- stage 4: all h (7 independent) ----
        #pragma unroll
        for (int m = 0; m < NF; ++m)
            hst[m] = (1.0f - ec[m]) *
                __builtin_amdgcn_rcpf((1.0f + e3[m]) * (1.0f + ec[m]));
    };

    #pragma unroll 1
    for (int g = 0; g < TSTEPS / 4; ++g) {
        // prefetch next 4-step group while computing this one
        const float4* __restrict__ pn =
            (const float4*)(xg + (size_t)((g < 127 ? g + 1 : 127) * 12));
        const float4 n0 = pn[0], n1 = pn[1], n2 = pn[2];
        step(a0.x, a0.y, a0.z);
        step(a0.w, a1.x, a1.y);
        step(a1.z, a1.w, a2.x);
        step(a2.y, a2.z, a2.w);
        a0 = n0; a1 = n1; a2 = n2;
    }

    // ---- final linear: out[b] = sum_u w_lin[u]*h[u] + b_lin ----
    const int ubase = (q == 0) ? 0 : (q == 1) ? 4 : (q == 2) ? 11 : 18;
    float v = 0.f;
    #pragma unroll
    for (int m = 0; m < NF; ++m) {
        if ((q != 0) || (m < 4)) v = fmaf(w_lin[ubase + m], hst[m], v);
    }
    v += __shfl_xor(v, 16);
    v += __shfl_xor(v, 32);
    if (lane < 16) out[b0 + n] = v + b_lin[0];
}

extern "C" void kernel_launch(void* const* d_in, const int* in_sizes, int n_in,
                              void* d_out, int out_size, void* d_ws, size_t ws_size,
                              hipStream_t stream) {
    const float* x     = (const float*)d_in[0];
    const float* w_ih  = (const float*)d_in[1];
    const float* w_hh  = (const float*)d_in[2];
    const float* b_ih  = (const float*)d_in[3];
    const float* b_hh  = (const float*)d_in[4];
    const float* w_lin = (const float*)d_in[5];
    const float* b_lin = (const float*)d_in[6];
    float* out = (float*)d_out;

    lstm_wave<<<8192 / 16, 64, 0, stream>>>(x, w_ih, w_hh, b_ih, b_hh,
                                            w_lin, b_lin, out);
}

// Round 7
// 257.505 us; speedup vs baseline: 1.5469x; 1.4274x over previous
//
#include <hip/hip_runtime.h>
#include <hip/hip_bf16.h>

// LSTM B=8192,T=512,I=3,H=25 + linear[H->1], bf16 MFMA 16x16x32.
// R19 (= R18 resubmit; round-6 bench was an infra failure, kernel unchanged
// except the barrier is now asm-waitcnt + __builtin_amdgcn_s_barrier()).
// R18: 4-WAVE BLOCKS - ALL 4 TRANS PIPES + CO-RESIDENT LATENCY HIDING.
// R15-R17 calibration: issue is serial per wave, trans = ~16cy/op; a
// single-wave chain needs 56 trans-ops/step = ~900cy through ONE SIMD's
// trans pipe, and only 2 of 4 SIMDs/CU are used. R12 (195us) won only by
// spreading trans over all 4 pipes. This kernel keeps that property while
// fixing R12's two costs:
//  - block = 4 waves = 1 chain; each wave: 2 MFMA row-blocks (jb=w, w+4;
//    jb=7 is a scrap block). 512 blocks -> 2 blocks/CU -> 2 waves/SIMD:
//    the OTHER block's wave hides this block's barrier+LDS latency.
//  - raw s_barrier + lgkmcnt(0) only (x-prefetch global loads stay in
//    flight across barriers; __syncthreads would drain vmcnt).
//  - merged-denominator c-update: 8 -> 7 trans/unit:
//    c' = [c(1+e0)(1+e2) + (1-e2)(1+e1)] / [(1+e0)(1+e1)(1+e2)]
//  - v2f glue across the wave's two row-blocks -> v_pk_* issue.
// Kept: R16 x-insert from registers (q0 lanes), frag-linear LDS (lane*16B
// ds_read_b128, conflict-free), pad-slot unmasked writes, -K1/-K2 fold.

#define TSTEPS 512
#define ISZ 3
#define HSZ 25

typedef __attribute__((ext_vector_type(8))) short bf16x8;
typedef __attribute__((ext_vector_type(4))) float f32x4;
typedef __attribute__((ext_vector_type(4))) int i32x4;
typedef __attribute__((ext_vector_type(2))) float v2f;

__device__ __forceinline__ unsigned short bf16_bits(float v) {
    return __builtin_bit_cast(unsigned short, __float2bfloat16(v));
}
__device__ __forceinline__ unsigned int pack_bf16(float lo, float hi) {
    return ((unsigned int)bf16_bits(hi) << 16) | (unsigned int)bf16_bits(lo);
}
__device__ __forceinline__ v2f rcp2(v2f v) {
    return (v2f){__builtin_amdgcn_rcpf(v.x), __builtin_amdgcn_rcpf(v.y)};
}

__global__ __launch_bounds__(256, 2) void lstm_mfma(
    const float* __restrict__ x,      // [B, T, I]
    const float* __restrict__ w_ih,   // [4H, I]
    const float* __restrict__ w_hh,   // [4H, H]
    const float* __restrict__ b_ih,   // [4H]
    const float* __restrict__ b_hh,   // [4H]
    const float* __restrict__ w_lin,  // [1, H]
    const float* __restrict__ b_lin,  // [1]
    float* __restrict__ out)          // [B, 1]
{
    // frag-linear: short idx (k,n) = (k>>3)*128 + n*8 + (k&7); real frag is
    // idx 0..511 (k<32); 512..767 is scrap for the jb=7 block's writes.
    __shared__ short hb[2][768];
    __shared__ float outred[4][16];

    const int tid  = threadIdx.x;
    const int w    = tid >> 6;        // wave 0..3
    const int lane = tid & 63;
    const int n    = lane & 15;       // batch col
    const int q    = lane >> 4;       // quad -> k-slots 8q..8q+7
    const int b0   = blockIdx.x * 16;

    const float K1 = 1.442695040888963f;   // log2 e
    const float K2 = 2.885390081777927f;   // 2 log2 e

    for (int i = tid; i < 2 * 768; i += 256) ((short*)hb)[i] = 0;

    // ---- A fragments for row-blocks jbA=w, jbB=w+4 (jb=7 all-zero) ----
    // Within a block: MFMA row rr=n -> unit 4*jb + (n>>2), gate n&3.
    // k map: 0..2 w_ih, 3 bias, 4..28 w_hh col k-4, 29..31 pad.
    bf16x8 afA, afB;
    {
        const int g = n & 3, us = n >> 2;
        const int uA = 4 * w + us;            // <= 15, always valid
        const int uB = 4 * (w + 4) + us;      // 16..31, guard < 25
        #pragma unroll
        for (int j = 0; j < 8; ++j) {
            const int k = q * 8 + j;
            float vA = 0.f, vB = 0.f;
            {
                const int orow = g * HSZ + uA;
                if (k < ISZ)            vA = w_ih[orow * ISZ + k];
                else if (k == ISZ)      vA = b_ih[orow] + b_hh[orow];
                else if (k < 4 + HSZ)   vA = w_hh[orow * HSZ + (k - 4)];
                vA *= (g == 2) ? -K2 : -K1;
            }
            if (uB < HSZ) {
                const int orow = g * HSZ + uB;
                if (k < ISZ)            vB = w_ih[orow * ISZ + k];
                else if (k == ISZ)      vB = b_ih[orow] + b_hh[orow];
                else if (k < 4 + HSZ)   vB = w_hh[orow * HSZ + (k - 4)];
                vB *= (g == 2) ? -K2 : -K1;
            }
            afA[j] = (short)bf16_bits(vA);
            afB[j] = (short)bf16_bits(vB);
        }
    }

    // ---- write slots: unit u=4jb+q -> k=u+4 (pads/scrap land harmlessly) --
    const int uwA = 4 * w + q;                 // <= 15
    const int uwB = 4 * (w + 4) + q;           // 16..31 (>=25 -> pad/scrap)
    const int kwA = uwA + 4, kwB = uwB + 4;    // kwB <= 35 -> scrap region
    const int woffA = (kwA >> 3) * 128 + n * 8 + (kwA & 7);
    const int woffB = (kwB >> 3) * 128 + n * 8 + (kwB & 7);
    const int rdoff = lane * 8;

    v2f c = {0.f, 0.f}, h = {0.f, 0.f};

    // ---- x prefetch: 3 x float4 per 4-step group, reg ping-pong ----
    const float* __restrict__ xg = x + (size_t)(b0 + n) * (TSTEPS * ISZ);
    float4 a0 = ((const float4*)xg)[0];
    float4 a1 = ((const float4*)xg)[1];
    float4 a2 = ((const float4*)xg)[2];

    __syncthreads();   // zeros visible (drains first prefetch once - ok)

    auto step = [&](int rp, float x0, float x1, float x2) {
        // linear ds_read_b128; q0 lanes insert x/bias from registers
        bf16x8 frag = *(const bf16x8*)&hb[rp][rdoff];
        i32x4 fi = __builtin_bit_cast(i32x4, frag);
        const int px0 = (int)pack_bf16(x0, x1);
        const int px1 = (int)pack_bf16(x2, 1.0f);
        fi[0] = (q == 0) ? px0 : fi[0];
        fi[1] = (q == 0) ? px1 : fi[1];
        frag = __builtin_bit_cast(bf16x8, fi);

        const f32x4 zc = {0.f, 0.f, 0.f, 0.f};
        const f32x4 aA = __builtin_amdgcn_mfma_f32_16x16x32_bf16(afA, frag, zc, 0, 0, 0);
        const f32x4 aB = __builtin_amdgcn_mfma_f32_16x16x32_bf16(afB, frag, zc, 0, 0, 0);

        // acts (prescaled): 14 trans; glue packed v2f across (A,B) blocks
        const v2f e0 = {__builtin_amdgcn_exp2f(aA[0]), __builtin_amdgcn_exp2f(aB[0])};
        const v2f e1 = {__builtin_amdgcn_exp2f(aA[1]), __builtin_amdgcn_exp2f(aB[1])};
        const v2f e2 = {__builtin_amdgcn_exp2f(fminf(aA[2], 126.f)),
                        __builtin_amdgcn_exp2f(fminf(aB[2], 126.f))};
        const v2f e3 = {__builtin_amdgcn_exp2f(aA[3]), __builtin_amdgcn_exp2f(aB[3])};
        const v2f one = {1.f, 1.f};
        const v2f s0 = e0 + one, s1 = e1 + one, s2 = e2 + one, m2 = one - e2;
        const v2f p02 = s0 * s2;
        const v2f num = c * p02 + m2 * s1;     // merged-denominator c-update
        const v2f den = p02 * s1;
        c = num * rcp2(den);
        const v2f ec = {__builtin_amdgcn_exp2f(fminf(-K2 * c.x, 126.f)),
                        __builtin_amdgcn_exp2f(fminf(-K2 * c.y, 126.f))};
        const v2f hden = (e3 + one) * (ec + one);
        h = (one - ec) * rcp2(hden);

        const int wp = rp ^ 1;
        hb[wp][woffA] = (short)bf16_bits(h.x);
        hb[wp][woffB] = (short)bf16_bits(h.y);   // pad/scrap-slot trick
        // retire DS writes, then barrier; vmcnt (x prefetch) stays in flight
        asm volatile("s_waitcnt lgkmcnt(0)" ::: "memory");
        __builtin_amdgcn_s_barrier();
    };

    #pragma unroll 1
    for (int g = 0; g < 128; g += 2) {
        const float4* __restrict__ p1 =
            (const float4*)(xg + (size_t)((g + 1 < 128 ? g + 1 : 127) * 12));
        const float4 n0 = p1[0], n1 = p1[1], n2 = p1[2];
        step(0, a0.x, a0.y, a0.z);
        step(1, a0.w, a1.x, a1.y);
        step(0, a1.z, a1.w, a2.x);
        step(1, a2.y, a2.z, a2.w);
        const float4* __restrict__ p2 =
            (const float4*)(xg + (size_t)((g + 2 < 128 ? g + 2 : 127) * 12));
        a0 = p2[0]; a1 = p2[1]; a2 = p2[2];
        step(0, n0.x, n0.y, n0.z);
        step(1, n0.w, n1.x, n1.y);
        step(0, n1.z, n1.w, n2.x);
        step(1, n2.y, n2.z, n2.w);
    }

    // ---- final linear: out[b] = sum_u w_lin[u]*h[u] + b_lin ----
    const float wlA = (uwA < HSZ) ? w_lin[uwA] : 0.f;
    const float wlB = (uwB < HSZ) ? w_lin[uwB] : 0.f;
    float v = wlA * h.x + wlB * h.y;
    v += __shfl_xor(v, 16);
    v += __shfl_xor(v, 32);
    if (lane < 16) outred[w][lane] = v;
    __syncthreads();
    if (tid < 16) {
        float s = b_lin[0];
        #pragma unroll
        for (int k2 = 0; k2 < 4; ++k2) s += outred[k2][tid];
        out[b0 + tid] = s;
    }
}

extern "C" void kernel_launch(void* const* d_in, const int* in_sizes, int n_in,
                              void* d_out, int out_size, void* d_ws, size_t ws_size,
                              hipStream_t stream) {
    const float* x     = (const float*)d_in[0];
    const float* w_ih  = (const float*)d_in[1];
    const float* w_hh  = (const float*)d_in[2];
    const float* b_ih  = (const float*)d_in[3];
    const float* b_hh  = (const float*)d_in[4];
    const float* w_lin = (const float*)d_in[5];
    const float* b_lin = (const float*)d_in[6];
    float* out = (float*)d_out;

    lstm_mfma<<<8192 / 16, 256, 0, stream>>>(x, w_ih, w_hh, b_ih, b_hh,
                                             w_lin, b_lin, out);
}